// Round 2
// baseline (24687.498 us; speedup 1.0000x reference)
//
#include <hip/hip_runtime.h>

// ---------------- problem constants ----------------
#define NN      16384      // total nodes
#define TSTEPS  32
#define SG      256        // graphs
#define NE      262144

// ---------------- workspace layout (float offsets) ----------------
#define OFF_ENC_MEM   0u
#define OFF_ENC_SPK   2097152u
#define OFF_C1_MEM    4194304u
#define OFF_C1_SPK    6291456u     // == xl [256][8192]
#define OFF_LH        8388608u
#define OFF_LC        8519680u
#define OFF_H1_MEM    8650752u
#define OFF_H1_SPK    8716288u
#define OFF_H2_MEM    8781824u
#define OFF_H2_SPK    8782848u
#define OFF_H2_SUM    8783872u
#define ZERO_FLOATS   8784896u     // everything below here zeroed each launch
#define OFF_BASES     8784896u
#define OFF_COMB      9833472u
#define OFF_GATES     10357760u    // 256 x 2048
#define OFF_DINV      10882048u
#define OFF_COLW      10898432u
#define FLOAT_END     11160576u
// int region (offsets from ibase)
#define IOFF_DEG      0
#define IOFF_FILL     16384
#define IOFF_ROWPTR   32768
#define IOFF_EID      49153
#define IOFF_COL      311297
#define INT_COUNT     573441

// ---------------- graph preprocessing ----------------
__global__ void k_deg(const int* __restrict__ ei, int* __restrict__ deg) {
  int e = blockIdx.x * 256 + threadIdx.x;
  if (e < NE) atomicAdd(&deg[ei[NE + e]], 1);
}

__global__ void k_dinv(const int* __restrict__ deg, float* __restrict__ dinv) {
  int n = blockIdx.x * 256 + threadIdx.x;
  if (n < NN) dinv[n] = __fdiv_rn(1.0f, __fsqrt_rn((float)(deg[n] + 1)));  // +1 self-loop
}

__global__ void k_scan(const int* __restrict__ deg, int* __restrict__ rowp) {
  __shared__ int sdata[1024];
  int tid = threadIdx.x;
  int base = tid * 16;
  int loc[16];
  int sum = 0;
  #pragma unroll
  for (int i = 0; i < 16; ++i) { loc[i] = sum; sum += deg[base + i]; }
  sdata[tid] = sum;
  __syncthreads();
  for (int off = 1; off < 1024; off <<= 1) {
    int v = 0;
    if (tid >= off) v = sdata[tid - off];
    __syncthreads();
    sdata[tid] += v;
    __syncthreads();
  }
  int excl = (tid == 0) ? 0 : sdata[tid - 1];
  #pragma unroll
  for (int i = 0; i < 16; ++i) rowp[base + i] = excl + loc[i];
  if (tid == 1023) rowp[NN] = sdata[1023];
}

__global__ void k_scatter(const int* __restrict__ ei, const int* __restrict__ rowp,
                          int* __restrict__ fill, int* __restrict__ eid) {
  int e = blockIdx.x * 256 + threadIdx.x;
  if (e >= NE) return;
  int d = ei[NE + e];
  int pos = rowp[d] + atomicAdd(&fill[d], 1);
  eid[pos] = e;
}

// sort each adjacency list by EDGE ID (unique keys) -> summation order == np.add.at /
// XLA scatter update order. Then materialize col (src) and colw (dinv[src]).
__global__ void k_sortadj(const int* __restrict__ rowp, int* __restrict__ eid,
                          const int* __restrict__ ei, const float* __restrict__ dinv,
                          int* __restrict__ col, float* __restrict__ colw) {
  int d = blockIdx.x * 256 + threadIdx.x;
  if (d >= NN) return;
  int r0 = rowp[d], r1 = rowp[d + 1];
  for (int i = r0 + 1; i < r1; ++i) {
    int key = eid[i];
    int j = i - 1;
    while (j >= r0 && eid[j] > key) { eid[j + 1] = eid[j]; --j; }
    eid[j + 1] = key;
  }
  for (int i = r0; i < r1; ++i) {
    int s = ei[eid[i]];
    col[i] = s;
    colw[i] = dinv[s];
  }
}

// ---------------- per-timestep kernels ----------------
// enc LIF: mem = (mem*0.2)*(1-spk) + x_t@enc_W + enc_b ; spk = mem > 0.5
__global__ __launch_bounds__(256) void k_enc(
    const float* __restrict__ x, const float* __restrict__ encW, const float* __restrict__ encB,
    float* __restrict__ enc_mem, float* __restrict__ enc_spk, int t) {
  int idx = blockIdx.x * 256 + threadIdx.x;   // n*128 + j
  int j = idx & 127, n = idx >> 7;
  const float* xp = x + (size_t)n * 256 + t;  // x[n][c][t], stride 32 over c
  float dot = 0.f;
  #pragma unroll
  for (int c = 0; c < 8; ++c) dot = __fmaf_rn(xp[c * 32], encW[c * 128 + j], dot);
  float m = enc_mem[idx], s = enc_spk[idx];
  float nm = __fadd_rn(__fadd_rn(__fmul_rn(__fmul_rn(m, 0.2f), __fsub_rn(1.f, s)), dot), encB[j]);
  enc_mem[idx] = nm;
  enc_spk[idx] = nm > 0.5f ? 1.f : 0.f;
}

// bases = spk @ bases_W + b ; comb = spk @ comb_W + b   (64 nodes/block, spikes in LDS)
#define NCHUNK 64
__global__ __launch_bounds__(256) void k_bases_comb(
    const float* __restrict__ enc_spk,
    const float* __restrict__ basesW, const float* __restrict__ basesB,
    const float* __restrict__ combW, const float* __restrict__ combB,
    float* __restrict__ bases, float* __restrict__ comb) {
  __shared__ float sp[NCHUNK * 128];
  int nb = blockIdx.x * NCHUNK;
  for (int i = threadIdx.x; i < NCHUNK * 128; i += 256)
    sp[i] = enc_spk[(size_t)nb * 128 + i];
  __syncthreads();
  for (int it = threadIdx.x; it < NCHUNK * 96; it += 256) {
    int nn = it / 96, m = it % 96;
    const float* srow = sp + nn * 128;
    if (m < 64) {
      float acc = 0.f;    // K=128 single BLAS panel, sequential fma (A binary -> == mul+add)
      #pragma unroll 8
      for (int j = 0; j < 128; ++j) acc = __fmaf_rn(srow[j], basesW[j * 64 + m], acc);
      bases[(size_t)(nb + nn) * 64 + m] = __fadd_rn(acc, basesB[m]);
    } else {
      int mm = m - 64;
      float acc = 0.f;
      #pragma unroll 8
      for (int j = 0; j < 128; ++j) acc = __fmaf_rn(srow[j], combW[j * 32 + mm], acc);
      comb[(size_t)(nb + nn) * 32 + mm] = __fadd_rn(acc, combB[mm]);
    }
  }
}

// fused: symnorm aggregation (edge-order scatter-add) -> einsum -> conv LIF -> c1 spike
__global__ __launch_bounds__(256) void k_aggconv(
    const float* __restrict__ bases, const float* __restrict__ comb,
    const float* __restrict__ dinv, const int* __restrict__ rowp,
    const int* __restrict__ col, const float* __restrict__ colw,
    const float* __restrict__ convB,
    float* __restrict__ c1_mem, float* __restrict__ c1_spk) {
  __shared__ float aggl[4][64];
  __shared__ float combl[4][32];
  int w = threadIdx.x >> 6;      // wave -> node within block
  int m = threadIdx.x & 63;      // channel of agg
  int d = blockIdx.x * 4 + w;
  float dd = dinv[d];
  int r0 = rowp[d], r1 = rowp[d + 1];
  float acc = 0.f;
  for (int r = r0; r < r1; ++r) {
    int s = col[r];
    float ew  = __fmul_rn(colw[r], dd);           // dinv[s]*dinv[d], per-op rounded
    float upd = __fmul_rn(ew, bases[(size_t)s * 64 + m]);
    acc = __fadd_rn(acc, upd);                    // scatter-add, edge order
  }
  {  // appended self-loop processed last (matches ref concat order)
    float ew  = __fmul_rn(dd, dd);
    float upd = __fmul_rn(ew, bases[(size_t)d * 64 + m]);
    acc = __fadd_rn(acc, upd);
  }
  aggl[w][m] = acc;
  if (m < 32) combl[w][m] = comb[(size_t)d * 32 + m];
  __syncthreads();
  #pragma unroll
  for (int half = 0; half < 2; ++half) {
    int j = m + half * 64;           // conv channel 0..127
    int h = j >> 4, f = j & 15;
    float cv = 0.f;                  // einsum over b: sequential mul+add (numpy einsum, no fma)
    #pragma unroll
    for (int b = 0; b < 4; ++b)
      cv = __fadd_rn(cv, __fmul_rn(combl[w][h * 4 + b], aggl[w][b * 16 + f]));
    cv = __fadd_rn(cv, convB[j]);    // + conv_bias
    int idx = d * 128 + j;
    float cm = c1_mem[idx], cs = c1_spk[idx];
    float nm = __fadd_rn(__fmul_rn(__fmul_rn(cm, 0.2f), __fsub_rn(1.f, cs)), cv);
    c1_mem[idx] = nm;
    c1_spk[idx] = nm > 0.5f ? 1.f : 0.f;
  }
}

// gates = xl@W_ih + b_ih + lh@W_hh + b_hh, each dot sequential-K with 384 panel grouping
// (BLAS sgemm emulation: per-panel fma chain from 0, C += panel). Tile 64x64, grid (32,4).
__global__ __launch_bounds__(256) void k_gates(
    const float* __restrict__ xl, const float* __restrict__ lh,
    const float* __restrict__ Wih, const float* __restrict__ Whh,
    const float* __restrict__ bih, const float* __restrict__ bhh,
    float* __restrict__ gates) {
  __shared__ __align__(16) float Ast[16][68];   // [k][m], row stride 68 keeps 16B alignment
  __shared__ __align__(16) float Bs[16][64];    // [k][n]
  const int tid = threadIdx.x;
  const int tx = tid & 15, ty = tid >> 4;
  const int n0 = blockIdx.x * 64;
  const int m0 = blockIdx.y * 64;
  const int ar = tid >> 2, ac = (tid & 3) * 4;   // A stage: 64 rows x 16 k
  const int bkr = tid >> 4, bc = (tid & 15) * 4; // B stage: 16 k x 64 n

  float tih[4][4], thh[4][4];
  #pragma unroll
  for (int i = 0; i < 4; ++i)
    #pragma unroll
    for (int j = 0; j < 4; ++j) { tih[i][j] = 0.f; thh[i][j] = 0.f; }

  #pragma unroll
  for (int seg = 0; seg < 2; ++seg) {
    const float* Asrc = seg ? lh : xl;
    const float* Bsrc = seg ? Whh : Wih;
    const int lda  = seg ? 512 : 8192;
    const int Klen = seg ? 512 : 8192;
    for (int p0 = 0; p0 < Klen; p0 += 384) {
      const int pend = (p0 + 384 < Klen) ? (p0 + 384) : Klen;
      float accP[4][4];
      #pragma unroll
      for (int i = 0; i < 4; ++i)
        #pragma unroll
        for (int j = 0; j < 4; ++j) accP[i][j] = 0.f;
      for (int kb = p0; kb < pend; kb += 16) {
        __syncthreads();
        const float4 av4 = *(const float4*)(Asrc + (size_t)(m0 + ar) * lda + kb + ac);
        Ast[ac + 0][ar] = av4.x; Ast[ac + 1][ar] = av4.y;
        Ast[ac + 2][ar] = av4.z; Ast[ac + 3][ar] = av4.w;
        *(float4*)&Bs[bkr][bc] = *(const float4*)(Bsrc + (size_t)(kb + bkr) * 2048 + n0 + bc);
        __syncthreads();
        #pragma unroll
        for (int kk = 0; kk < 16; ++kk) {
          const float4 a4 = *(const float4*)&Ast[kk][ty * 4];
          const float4 b4 = *(const float4*)&Bs[kk][tx * 4];
          const float av[4] = {a4.x, a4.y, a4.z, a4.w};
          const float bv[4] = {b4.x, b4.y, b4.z, b4.w};
          #pragma unroll
          for (int i = 0; i < 4; ++i)
            #pragma unroll
            for (int j = 0; j < 4; ++j)
              accP[i][j] = __fmaf_rn(av[i], bv[j], accP[i][j]);
        }
      }
      #pragma unroll
      for (int i = 0; i < 4; ++i)
        #pragma unroll
        for (int j = 0; j < 4; ++j) {
          if (seg == 0) tih[i][j] = __fadd_rn(tih[i][j], accP[i][j]);
          else          thh[i][j] = __fadd_rn(thh[i][j], accP[i][j]);
        }
    }
  }
  #pragma unroll
  for (int i = 0; i < 4; ++i)
    #pragma unroll
    for (int j = 0; j < 4; ++j) {
      const int m = m0 + ty * 4 + i, u = n0 + tx * 4 + j;
      // ref order: ((xl@Wih + b_ih) + lh@Whh) + b_hh
      float g = __fadd_rn(__fadd_rn(__fadd_rn(tih[i][j], bih[u]), thh[i][j]), bhh[u]);
      gates[(size_t)m * 2048 + u] = g;
    }
}

// fused: gate spikes -> LSTM cell -> fc1 LIF (384+128 panels) -> fc2 LIF (sequential) -> h2 accum
__global__ __launch_bounds__(256) void k_cell(
    const float* __restrict__ gates,
    float* __restrict__ lc, float* __restrict__ lh,
    const float* __restrict__ fc1W, const float* __restrict__ fc1b,
    const float* __restrict__ fc2W, const float* __restrict__ fc2b,
    float* __restrict__ h1_mem, float* __restrict__ h1_spk,
    float* __restrict__ h2_mem, float* __restrict__ h2_spk, float* __restrict__ h2_sum) {
  __shared__ float lhl[512];
  __shared__ float sp1l[256];
  const int s = blockIdx.x;
  const int p = threadIdx.x;
  #pragma unroll
  for (int half = 0; half < 2; ++half) {
    const int h = p + half * 256;
    const float giv = gates[(size_t)s * 2048 + h];
    const float gfv = gates[(size_t)s * 2048 + 512 + h];
    const float ggv = gates[(size_t)s * 2048 + 1024 + h];
    const float gov = gates[(size_t)s * 2048 + 1536 + h];
    const float iv = giv > 0.f ? 1.f : 0.f;
    const float fv = gfv > 0.f ? 1.f : 0.f;
    const float gv = ggv > 0.f ? 1.f : 0.f;
    const float ov = gov > 0.f ? 1.f : 0.f;
    const int li = s * 512 + h;
    const float lcv = __fadd_rn(__fmul_rn(fv, lc[li]), __fmul_rn(iv, gv));
    lc[li] = lcv;
    const float lhv = __fmul_rn(lcv, ov);
    lh[li] = lhv;
    lhl[h] = lhv;
  }
  __syncthreads();
  // fc1: K=512 -> BLAS panels 384 + 128
  float a0 = 0.f, a1 = 0.f;
  #pragma unroll 8
  for (int q = 0; q < 384; ++q) a0 = __fmaf_rn(lhl[q], fc1W[q * 256 + p], a0);
  #pragma unroll 8
  for (int q = 384; q < 512; ++q) a1 = __fmaf_rn(lhl[q], fc1W[q * 256 + p], a1);
  const float dot1 = __fadd_rn(a0, a1);
  const int i1 = s * 256 + p;
  const float m1 = h1_mem[i1], s1o = h1_spk[i1];
  const float nm1 = __fadd_rn(__fadd_rn(__fmul_rn(__fmul_rn(m1, 0.2f), __fsub_rn(1.f, s1o)), dot1), fc1b[p]);
  h1_mem[i1] = nm1;
  const float sp1 = nm1 > 0.5f ? 1.f : 0.f;
  h1_spk[i1] = sp1;
  sp1l[p] = sp1;
  __syncthreads();
  if (p < 4) {
    float acc = 0.f;   // K=256 single panel, sequential (h1_spk binary -> fma == mul+add)
    for (int q = 0; q < 256; ++q) acc = __fmaf_rn(sp1l[q], fc2W[q * 4 + p], acc);
    const int i2 = s * 4 + p;
    const float m2 = h2_mem[i2], s2o = h2_spk[i2];
    const float nm2 = __fadd_rn(__fadd_rn(__fmul_rn(__fmul_rn(m2, 0.2f), __fsub_rn(1.f, s2o)), acc), fc2b[p]);
    h2_mem[i2] = nm2;
    const float sp2 = nm2 > 0.5f ? 1.f : 0.f;
    h2_spk[i2] = sp2;
    h2_sum[i2] = __fadd_rn(h2_sum[i2], sp2);
  }
}

__global__ void k_out(const float* __restrict__ h2_sum, float* __restrict__ out) {
  int i = blockIdx.x * 256 + threadIdx.x;
  if (i < SG * 4) out[i] = __fmul_rn(h2_sum[i], 0.03125f);  // /32 exact (pow2)
}

// ---------------- launch ----------------
extern "C" void kernel_launch(void* const* d_in, const int* in_sizes, int n_in,
                              void* d_out, int out_size, void* d_ws, size_t ws_size,
                              hipStream_t stream) {
  const float* x      = (const float*)d_in[0];
  const int*   ei     = (const int*)  d_in[1];
  const float* encW   = (const float*)d_in[2];
  const float* encB   = (const float*)d_in[3];
  const float* basesW = (const float*)d_in[4];
  const float* basesB = (const float*)d_in[5];
  const float* combW  = (const float*)d_in[6];
  const float* combB  = (const float*)d_in[7];
  const float* convB  = (const float*)d_in[8];
  const float* Wih    = (const float*)d_in[9];
  const float* Whh    = (const float*)d_in[10];
  const float* bih    = (const float*)d_in[11];
  const float* bhh    = (const float*)d_in[12];
  const float* fc1W   = (const float*)d_in[13];
  const float* fc1b   = (const float*)d_in[14];
  const float* fc2W   = (const float*)d_in[15];
  const float* fc2b   = (const float*)d_in[16];

  float* ws = (float*)d_ws;
  float* enc_mem = ws + OFF_ENC_MEM;
  float* enc_spk = ws + OFF_ENC_SPK;
  float* c1_mem  = ws + OFF_C1_MEM;
  float* c1_spk  = ws + OFF_C1_SPK;   // xl
  float* lhp     = ws + OFF_LH;
  float* lcp     = ws + OFF_LC;
  float* h1_mem  = ws + OFF_H1_MEM;
  float* h1_spk  = ws + OFF_H1_SPK;
  float* h2_mem  = ws + OFF_H2_MEM;
  float* h2_spk  = ws + OFF_H2_SPK;
  float* h2_sum  = ws + OFF_H2_SUM;
  float* bases   = ws + OFF_BASES;
  float* comb    = ws + OFF_COMB;
  float* gates   = ws + OFF_GATES;
  float* dinv    = ws + OFF_DINV;
  float* colw    = ws + OFF_COLW;
  int* ibase = (int*)((char*)d_ws + (size_t)FLOAT_END * 4);
  int* deg  = ibase + IOFF_DEG;
  int* fill = ibase + IOFF_FILL;
  int* rowp = ibase + IOFF_ROWPTR;
  int* eid  = ibase + IOFF_EID;
  int* col  = ibase + IOFF_COL;

  // zero persistent state + counters (ws is poisoned 0xAA before every call)
  hipMemsetAsync(ws, 0, (size_t)ZERO_FLOATS * 4, stream);
  hipMemsetAsync(ibase, 0, 32768 * 4, stream);

  // graph preprocessing (edge_index fixed across timesteps)
  k_deg    <<<NE / 256, 256, 0, stream>>>(ei, deg);
  k_dinv   <<<NN / 256, 256, 0, stream>>>(deg, dinv);
  k_scan   <<<1, 1024, 0, stream>>>(deg, rowp);
  k_scatter<<<NE / 256, 256, 0, stream>>>(ei, rowp, fill, eid);
  k_sortadj<<<NN / 256, 256, 0, stream>>>(rowp, eid, ei, dinv, col, colw);

  for (int t = 0; t < TSTEPS; ++t) {
    k_enc       <<<NN * 128 / 256, 256, 0, stream>>>(x, encW, encB, enc_mem, enc_spk, t);
    k_bases_comb<<<NN / NCHUNK, 256, 0, stream>>>(enc_spk, basesW, basesB, combW, combB, bases, comb);
    k_aggconv   <<<NN / 4, 256, 0, stream>>>(bases, comb, dinv, rowp, col, colw, convB, c1_mem, c1_spk);
    k_gates     <<<dim3(32, 4), 256, 0, stream>>>(c1_spk, lhp, Wih, Whh, bih, bhh, gates);
    k_cell      <<<SG, 256, 0, stream>>>(gates, lcp, lhp, fc1W, fc1b, fc2W, fc2b,
                                         h1_mem, h1_spk, h2_mem, h2_spk, h2_sum);
  }
  k_out<<<4, 256, 0, stream>>>(h2_sum, (float*)d_out);
}

// Round 3
// 10080.416 us; speedup vs baseline: 2.4491x; 2.4491x over previous
//
#include <hip/hip_runtime.h>

// ---------------- problem constants ----------------
#define NN      16384      // total nodes
#define TSTEPS  32
#define SG      256        // graphs
#define NE      262144
#define NPANEL  24         // 22 panels for xl@Wih (21x384 + 128) + 2 for lh@Whh (384+128)
#define GSTRIDE 524288u    // 256*2048 floats per panel partial

// ---------------- workspace layout (float offsets) ----------------
#define OFF_ENC_MEM   0u
#define OFF_ENC_SPK   2097152u
#define OFF_C1_MEM    4194304u
#define OFF_C1_SPK    6291456u     // == xl [256][8192]
#define OFF_LH        8388608u
#define OFF_LC        8519680u
#define OFF_H1_MEM    8650752u
#define OFF_H1_SPK    8716288u
#define OFF_H2_MEM    8781824u
#define OFF_H2_SPK    8782848u
#define OFF_H2_SUM    8783872u
#define ZERO_FLOATS   8784896u     // everything below here zeroed each launch
#define OFF_BASES     8784896u
#define OFF_COMB      9833472u
#define OFF_GATES     10357760u    // 256 x 2048
#define OFF_PART      10882048u    // 24 x 256 x 2048 panel partials
#define OFF_DINV      23464960u
#define OFF_COLW      23481344u
#define FLOAT_END     23743488u
// int region (offsets from ibase)
#define IOFF_DEG      0
#define IOFF_FILL     16384
#define IOFF_ROWPTR   32768
#define IOFF_EID      49153
#define IOFF_COL      311297
#define INT_COUNT     573441

// ---------------- graph preprocessing ----------------
__global__ void k_deg(const int* __restrict__ ei, int* __restrict__ deg) {
  int e = blockIdx.x * 256 + threadIdx.x;
  if (e < NE) atomicAdd(&deg[ei[NE + e]], 1);
}

__global__ void k_dinv(const int* __restrict__ deg, float* __restrict__ dinv) {
  int n = blockIdx.x * 256 + threadIdx.x;
  if (n < NN) dinv[n] = __fdiv_rn(1.0f, __fsqrt_rn((float)(deg[n] + 1)));  // +1 self-loop
}

__global__ void k_scan(const int* __restrict__ deg, int* __restrict__ rowp) {
  __shared__ int sdata[1024];
  int tid = threadIdx.x;
  int base = tid * 16;
  int loc[16];
  int sum = 0;
  #pragma unroll
  for (int i = 0; i < 16; ++i) { loc[i] = sum; sum += deg[base + i]; }
  sdata[tid] = sum;
  __syncthreads();
  for (int off = 1; off < 1024; off <<= 1) {
    int v = 0;
    if (tid >= off) v = sdata[tid - off];
    __syncthreads();
    sdata[tid] += v;
    __syncthreads();
  }
  int excl = (tid == 0) ? 0 : sdata[tid - 1];
  #pragma unroll
  for (int i = 0; i < 16; ++i) rowp[base + i] = excl + loc[i];
  if (tid == 1023) rowp[NN] = sdata[1023];
}

__global__ void k_scatter(const int* __restrict__ ei, const int* __restrict__ rowp,
                          int* __restrict__ fill, int* __restrict__ eid) {
  int e = blockIdx.x * 256 + threadIdx.x;
  if (e >= NE) return;
  int d = ei[NE + e];
  int pos = rowp[d] + atomicAdd(&fill[d], 1);
  eid[pos] = e;
}

// sort each adjacency list by EDGE ID (unique keys) -> summation order == scatter-add order
__global__ void k_sortadj(const int* __restrict__ rowp, int* __restrict__ eid,
                          const int* __restrict__ ei, const float* __restrict__ dinv,
                          int* __restrict__ col, float* __restrict__ colw) {
  int d = blockIdx.x * 256 + threadIdx.x;
  if (d >= NN) return;
  int r0 = rowp[d], r1 = rowp[d + 1];
  for (int i = r0 + 1; i < r1; ++i) {
    int key = eid[i];
    int j = i - 1;
    while (j >= r0 && eid[j] > key) { eid[j + 1] = eid[j]; --j; }
    eid[j + 1] = key;
  }
  for (int i = r0; i < r1; ++i) {
    int s = ei[eid[i]];
    col[i] = s;
    colw[i] = dinv[s];
  }
}

// ---------------- per-timestep kernels ----------------
// enc LIF (2 nodes/block; x staged through LDS to kill strided scalar loads)
__global__ __launch_bounds__(256) void k_enc(
    const float* __restrict__ x, const float* __restrict__ encW, const float* __restrict__ encB,
    float* __restrict__ enc_mem, float* __restrict__ enc_spk, int t) {
  __shared__ float xs[2][8];
  int tid = threadIdx.x;
  int nb = blockIdx.x * 2;
  if (tid < 16)
    xs[tid >> 3][tid & 7] = x[(size_t)(nb + (tid >> 3)) * 256 + (size_t)(tid & 7) * 32 + t];
  __syncthreads();
  int nl = tid >> 7, j = tid & 127;
  int idx = (nb + nl) * 128 + j;
  float dot = 0.f;
  #pragma unroll
  for (int c = 0; c < 8; ++c) dot = __fmaf_rn(xs[nl][c], encW[c * 128 + j], dot);
  float m = enc_mem[idx], s = enc_spk[idx];
  float nm = __fadd_rn(__fadd_rn(__fmul_rn(__fmul_rn(m, 0.2f), __fsub_rn(1.f, s)), dot), encB[j]);
  enc_mem[idx] = nm;
  enc_spk[idx] = nm > 0.5f ? 1.f : 0.f;
}

// bases = spk @ bases_W + b ; comb = spk @ comb_W + b
#define NCHUNK 64
__global__ __launch_bounds__(256) void k_bases_comb(
    const float* __restrict__ enc_spk,
    const float* __restrict__ basesW, const float* __restrict__ basesB,
    const float* __restrict__ combW, const float* __restrict__ combB,
    float* __restrict__ bases, float* __restrict__ comb) {
  __shared__ float sp[NCHUNK * 128];
  int nb = blockIdx.x * NCHUNK;
  for (int i = threadIdx.x; i < NCHUNK * 128; i += 256)
    sp[i] = enc_spk[(size_t)nb * 128 + i];
  __syncthreads();
  for (int it = threadIdx.x; it < NCHUNK * 96; it += 256) {
    int nn = it / 96, m = it % 96;
    const float* srow = sp + nn * 128;
    if (m < 64) {
      float acc = 0.f;
      #pragma unroll 8
      for (int j = 0; j < 128; ++j) acc = __fmaf_rn(srow[j], basesW[j * 64 + m], acc);
      bases[(size_t)(nb + nn) * 64 + m] = __fadd_rn(acc, basesB[m]);
    } else {
      int mm = m - 64;
      float acc = 0.f;
      #pragma unroll 8
      for (int j = 0; j < 128; ++j) acc = __fmaf_rn(srow[j], combW[j * 32 + mm], acc);
      comb[(size_t)(nb + nn) * 32 + mm] = __fadd_rn(acc, combB[mm]);
    }
  }
}

// fused: symnorm aggregation (edge-order scatter-add) -> einsum -> conv LIF -> c1 spike
__global__ __launch_bounds__(256) void k_aggconv(
    const float* __restrict__ bases, const float* __restrict__ comb,
    const float* __restrict__ dinv, const int* __restrict__ rowp,
    const int* __restrict__ col, const float* __restrict__ colw,
    const float* __restrict__ convB,
    float* __restrict__ c1_mem, float* __restrict__ c1_spk) {
  __shared__ float aggl[4][64];
  __shared__ float combl[4][32];
  int w = threadIdx.x >> 6;
  int m = threadIdx.x & 63;
  int d = blockIdx.x * 4 + w;
  float dd = dinv[d];
  int r0 = rowp[d], r1 = rowp[d + 1];
  float acc = 0.f;
  for (int r = r0; r < r1; ++r) {
    int s = col[r];
    float ew  = __fmul_rn(colw[r], dd);
    float upd = __fmul_rn(ew, bases[(size_t)s * 64 + m]);
    acc = __fadd_rn(acc, upd);
  }
  {
    float ew  = __fmul_rn(dd, dd);
    float upd = __fmul_rn(ew, bases[(size_t)d * 64 + m]);
    acc = __fadd_rn(acc, upd);
  }
  aggl[w][m] = acc;
  if (m < 32) combl[w][m] = comb[(size_t)d * 32 + m];
  __syncthreads();
  #pragma unroll
  for (int half = 0; half < 2; ++half) {
    int j = m + half * 64;
    int h = j >> 4, f = j & 15;
    float cv = 0.f;
    #pragma unroll
    for (int b = 0; b < 4; ++b)
      cv = __fadd_rn(cv, __fmul_rn(combl[w][h * 4 + b], aggl[w][b * 16 + f]));
    cv = __fadd_rn(cv, convB[j]);
    int idx = d * 128 + j;
    float cm = c1_mem[idx], cs = c1_spk[idx];
    float nm = __fadd_rn(__fmul_rn(__fmul_rn(cm, 0.2f), __fsub_rn(1.f, cs)), cv);
    c1_mem[idx] = nm;
    c1_spk[idx] = nm > 0.5f ? 1.f : 0.f;
  }
}

// one BLAS panel of the gates GEMM: part[z] = A[:, panel_z] @ B[panel_z, :]
// Panels are independent fma chains from 0 (ascending k), so K-parallelism is
// bit-exact. Tile 128x128, 256 threads, 8x8 reg tile (4+4 split columns/rows
// so every ds_read_b128 covers a contiguous 256B span -> 2-way wrap = free).
__global__ __launch_bounds__(256) void k_gpanel(
    const float* __restrict__ xl, const float* __restrict__ lh,
    const float* __restrict__ Wih, const float* __restrict__ Whh,
    float* __restrict__ part) {
  __shared__ __align__(16) float Ast[16][132];   // [k][m] transposed
  __shared__ __align__(16) float Bs[16][132];    // [k][n]
  const int tid = threadIdx.x;
  const int tx = tid & 15, ty = tid >> 4;
  const int n0 = blockIdx.x * 128;
  const int m0 = blockIdx.y * 128;
  const int z  = blockIdx.z;

  const float* Asrc; const float* Bsrc; int lda, k0, klen;
  if (z < 22) { Asrc = xl; Bsrc = Wih; lda = 8192; k0 = z * 384; klen = (z == 21) ? 128 : 384; }
  else        { Asrc = lh; Bsrc = Whh; lda = 512;  k0 = (z == 22) ? 0 : 384; klen = (z == 22) ? 384 : 128; }

  float acc[8][8];
  #pragma unroll
  for (int i = 0; i < 8; ++i)
    #pragma unroll
    for (int j = 0; j < 8; ++j) acc[i][j] = 0.f;

  const int arow = tid >> 1;            // 0..127
  const int acol = (tid & 1) * 8;       // 0 or 8
  const int brow = tid >> 5;            // 0..7 (and +8)
  const int bcol = (tid & 31) * 4;      // 0..124

  const int nkt = klen >> 4;
  for (int kt = 0; kt < nkt; ++kt) {
    const int kb = k0 + (kt << 4);
    __syncthreads();
    {   // A tile -> transposed LDS
      const float* src = Asrc + (size_t)(m0 + arow) * lda + kb + acol;
      const float4 v0 = ((const float4*)src)[0];
      const float4 v1 = ((const float4*)src)[1];
      Ast[acol + 0][arow] = v0.x; Ast[acol + 1][arow] = v0.y;
      Ast[acol + 2][arow] = v0.z; Ast[acol + 3][arow] = v0.w;
      Ast[acol + 4][arow] = v1.x; Ast[acol + 5][arow] = v1.y;
      Ast[acol + 6][arow] = v1.z; Ast[acol + 7][arow] = v1.w;
    }
    {   // B tile (2 rows per thread, fully coalesced 16B chunks)
      *(float4*)&Bs[brow][bcol] =
          *(const float4*)(Bsrc + (size_t)(kb + brow) * 2048 + n0 + bcol);
      *(float4*)&Bs[brow + 8][bcol] =
          *(const float4*)(Bsrc + (size_t)(kb + brow + 8) * 2048 + n0 + bcol);
    }
    __syncthreads();
    #pragma unroll
    for (int kk = 0; kk < 16; ++kk) {
      const float4 a0 = *(const float4*)&Ast[kk][ty * 4];
      const float4 a1 = *(const float4*)&Ast[kk][64 + ty * 4];
      const float4 b0 = *(const float4*)&Bs[kk][tx * 4];
      const float4 b1 = *(const float4*)&Bs[kk][64 + tx * 4];
      const float av[8] = {a0.x, a0.y, a0.z, a0.w, a1.x, a1.y, a1.z, a1.w};
      const float bv[8] = {b0.x, b0.y, b0.z, b0.w, b1.x, b1.y, b1.z, b1.w};
      #pragma unroll
      for (int i = 0; i < 8; ++i)
        #pragma unroll
        for (int j = 0; j < 8; ++j)
          acc[i][j] = __fmaf_rn(av[i], bv[j], acc[i][j]);
    }
  }
  // write panel partial: rows {i>>2}*64 + ty*4 + (i&3), cols {j>>2}*64 + tx*4 + (j&3)
  float* dstz = part + (size_t)z * GSTRIDE + (size_t)m0 * 2048 + n0;
  #pragma unroll
  for (int i = 0; i < 8; ++i) {
    const int mr = ((i >> 2) << 6) + ty * 4 + (i & 3);
    float* row = dstz + (size_t)mr * 2048;
    *(float4*)(row + tx * 4)      = make_float4(acc[i][0], acc[i][1], acc[i][2], acc[i][3]);
    *(float4*)(row + 64 + tx * 4) = make_float4(acc[i][4], acc[i][5], acc[i][6], acc[i][7]);
  }
}

// combine panel partials strictly left-to-right (matches round-2 "tih += accP" chain)
__global__ __launch_bounds__(256) void k_combine(
    const float* __restrict__ part, const float* __restrict__ bih,
    const float* __restrict__ bhh, float* __restrict__ gates) {
  const int idx = blockIdx.x * 256 + threadIdx.x;    // m*2048 + u
  const float* p = part + idx;
  float tih = p[0];
  #pragma unroll
  for (int zz = 1; zz < 22; ++zz) tih = __fadd_rn(tih, p[(size_t)zz * GSTRIDE]);
  const float thh = __fadd_rn(p[22u * GSTRIDE], p[23u * GSTRIDE]);
  const int u = idx & 2047;
  gates[idx] = __fadd_rn(__fadd_rn(__fadd_rn(tih, bih[u]), thh), bhh[u]);
}

// fused: gate spikes -> LSTM cell -> fc1 LIF (384+128 panels) -> fc2 LIF -> h2 accum
__global__ __launch_bounds__(256) void k_cell(
    const float* __restrict__ gates,
    float* __restrict__ lc, float* __restrict__ lh,
    const float* __restrict__ fc1W, const float* __restrict__ fc1b,
    const float* __restrict__ fc2W, const float* __restrict__ fc2b,
    float* __restrict__ h1_mem, float* __restrict__ h1_spk,
    float* __restrict__ h2_mem, float* __restrict__ h2_spk, float* __restrict__ h2_sum) {
  __shared__ float lhl[512];
  __shared__ float sp1l[256];
  const int s = blockIdx.x;
  const int p = threadIdx.x;
  #pragma unroll
  for (int half = 0; half < 2; ++half) {
    const int h = p + half * 256;
    const float giv = gates[(size_t)s * 2048 + h];
    const float gfv = gates[(size_t)s * 2048 + 512 + h];
    const float ggv = gates[(size_t)s * 2048 + 1024 + h];
    const float gov = gates[(size_t)s * 2048 + 1536 + h];
    const float iv = giv > 0.f ? 1.f : 0.f;
    const float fv = gfv > 0.f ? 1.f : 0.f;
    const float gv = ggv > 0.f ? 1.f : 0.f;
    const float ov = gov > 0.f ? 1.f : 0.f;
    const int li = s * 512 + h;
    const float lcv = __fadd_rn(__fmul_rn(fv, lc[li]), __fmul_rn(iv, gv));
    lc[li] = lcv;
    const float lhv = __fmul_rn(lcv, ov);
    lh[li] = lhv;
    lhl[h] = lhv;
  }
  __syncthreads();
  float a0 = 0.f, a1 = 0.f;
  #pragma unroll 8
  for (int q = 0; q < 384; ++q) a0 = __fmaf_rn(lhl[q], fc1W[q * 256 + p], a0);
  #pragma unroll 8
  for (int q = 384; q < 512; ++q) a1 = __fmaf_rn(lhl[q], fc1W[q * 256 + p], a1);
  const float dot1 = __fadd_rn(a0, a1);
  const int i1 = s * 256 + p;
  const float m1 = h1_mem[i1], s1o = h1_spk[i1];
  const float nm1 = __fadd_rn(__fadd_rn(__fmul_rn(__fmul_rn(m1, 0.2f), __fsub_rn(1.f, s1o)), dot1), fc1b[p]);
  h1_mem[i1] = nm1;
  const float sp1 = nm1 > 0.5f ? 1.f : 0.f;
  h1_spk[i1] = sp1;
  sp1l[p] = sp1;
  __syncthreads();
  if (p < 4) {
    float acc = 0.f;
    for (int q = 0; q < 256; ++q) acc = __fmaf_rn(sp1l[q], fc2W[q * 4 + p], acc);
    const int i2 = s * 4 + p;
    const float m2 = h2_mem[i2], s2o = h2_spk[i2];
    const float nm2 = __fadd_rn(__fadd_rn(__fmul_rn(__fmul_rn(m2, 0.2f), __fsub_rn(1.f, s2o)), acc), fc2b[p]);
    h2_mem[i2] = nm2;
    const float sp2 = nm2 > 0.5f ? 1.f : 0.f;
    h2_spk[i2] = sp2;
    h2_sum[i2] = __fadd_rn(h2_sum[i2], sp2);
  }
}

__global__ void k_out(const float* __restrict__ h2_sum, float* __restrict__ out) {
  int i = blockIdx.x * 256 + threadIdx.x;
  if (i < SG * 4) out[i] = __fmul_rn(h2_sum[i], 0.03125f);
}

// ---------------- launch ----------------
extern "C" void kernel_launch(void* const* d_in, const int* in_sizes, int n_in,
                              void* d_out, int out_size, void* d_ws, size_t ws_size,
                              hipStream_t stream) {
  const float* x      = (const float*)d_in[0];
  const int*   ei     = (const int*)  d_in[1];
  const float* encW   = (const float*)d_in[2];
  const float* encB   = (const float*)d_in[3];
  const float* basesW = (const float*)d_in[4];
  const float* basesB = (const float*)d_in[5];
  const float* combW  = (const float*)d_in[6];
  const float* combB  = (const float*)d_in[7];
  const float* convB  = (const float*)d_in[8];
  const float* Wih    = (const float*)d_in[9];
  const float* Whh    = (const float*)d_in[10];
  const float* bih    = (const float*)d_in[11];
  const float* bhh    = (const float*)d_in[12];
  const float* fc1W   = (const float*)d_in[13];
  const float* fc1b   = (const float*)d_in[14];
  const float* fc2W   = (const float*)d_in[15];
  const float* fc2b   = (const float*)d_in[16];

  float* ws = (float*)d_ws;
  float* enc_mem = ws + OFF_ENC_MEM;
  float* enc_spk = ws + OFF_ENC_SPK;
  float* c1_mem  = ws + OFF_C1_MEM;
  float* c1_spk  = ws + OFF_C1_SPK;   // xl
  float* lhp     = ws + OFF_LH;
  float* lcp     = ws + OFF_LC;
  float* h1_mem  = ws + OFF_H1_MEM;
  float* h1_spk  = ws + OFF_H1_SPK;
  float* h2_mem  = ws + OFF_H2_MEM;
  float* h2_spk  = ws + OFF_H2_SPK;
  float* h2_sum  = ws + OFF_H2_SUM;
  float* bases   = ws + OFF_BASES;
  float* comb    = ws + OFF_COMB;
  float* gates   = ws + OFF_GATES;
  float* partp   = ws + OFF_PART;
  float* dinv    = ws + OFF_DINV;
  float* colw    = ws + OFF_COLW;
  int* ibase = (int*)((char*)d_ws + (size_t)FLOAT_END * 4);
  int* deg  = ibase + IOFF_DEG;
  int* fill = ibase + IOFF_FILL;
  int* rowp = ibase + IOFF_ROWPTR;
  int* eid  = ibase + IOFF_EID;
  int* col  = ibase + IOFF_COL;

  hipMemsetAsync(ws, 0, (size_t)ZERO_FLOATS * 4, stream);
  hipMemsetAsync(ibase, 0, 32768 * 4, stream);

  k_deg    <<<NE / 256, 256, 0, stream>>>(ei, deg);
  k_dinv   <<<NN / 256, 256, 0, stream>>>(deg, dinv);
  k_scan   <<<1, 1024, 0, stream>>>(deg, rowp);
  k_scatter<<<NE / 256, 256, 0, stream>>>(ei, rowp, fill, eid);
  k_sortadj<<<NN / 256, 256, 0, stream>>>(rowp, eid, ei, dinv, col, colw);

  for (int t = 0; t < TSTEPS; ++t) {
    k_enc       <<<NN / 2, 256, 0, stream>>>(x, encW, encB, enc_mem, enc_spk, t);
    k_bases_comb<<<NN / NCHUNK, 256, 0, stream>>>(enc_spk, basesW, basesB, combW, combB, bases, comb);
    k_aggconv   <<<NN / 4, 256, 0, stream>>>(bases, comb, dinv, rowp, col, colw, convB, c1_mem, c1_spk);
    k_gpanel    <<<dim3(16, 2, NPANEL), 256, 0, stream>>>(c1_spk, lhp, Wih, Whh, partp);
    k_combine   <<<2048, 256, 0, stream>>>(partp, bih, bhh, gates);
    k_cell      <<<SG, 256, 0, stream>>>(gates, lcp, lhp, fc1W, fc1b, fc2W, fc2b,
                                         h1_mem, h1_spk, h2_mem, h2_spk, h2_sum);
  }
  k_out<<<4, 256, 0, stream>>>(h2_sum, (float*)d_out);
}

// Round 4
// 7217.918 us; speedup vs baseline: 3.4203x; 1.3966x over previous
//
#include <hip/hip_runtime.h>

// ---------------- problem constants ----------------
#define NN      16384      // total nodes
#define TSTEPS  32
#define SG      256        // graphs
#define NE      262144
#define NPANEL  24         // 22 panels for xl@Wih (21x384 + 128) + 2 for lh@Whh (384+128)
#define GSTRIDE 524288u    // 256*2048 floats per panel partial

// ---------------- workspace layout (float offsets) ----------------
#define OFF_ENC_MEM   0u
#define OFF_ENC_SPK   2097152u
#define OFF_C1_MEM    4194304u
#define OFF_C1_SPK    6291456u     // == xl [256][8192]
#define OFF_LH        8388608u
#define OFF_LC        8519680u
#define OFF_H1_MEM    8650752u
#define OFF_H1_SPK    8716288u
#define OFF_H2_MEM    8781824u
#define OFF_H2_SPK    8782848u
#define OFF_H2_SUM    8783872u
#define ZERO_FLOATS   8784896u     // everything below here zeroed each launch
#define OFF_BASES     8784896u
#define OFF_COMB      9833472u
#define OFF_GATES     10357760u    // 256 x 2048
#define OFF_PART      10882048u    // 24 x 256 x 2048 panel partials
#define OFF_DINV      23464960u
#define OFF_COLW      23481344u
#define FLOAT_END     23743488u
// int region (offsets from ibase)
#define IOFF_DEG      0
#define IOFF_FILL     16384
#define IOFF_ROWPTR   32768
#define IOFF_EID      49153
#define IOFF_COL      311297
#define INT_COUNT     573441

// ---------------- graph preprocessing ----------------
__global__ void k_deg(const int* __restrict__ ei, int* __restrict__ deg) {
  int e = blockIdx.x * 256 + threadIdx.x;
  if (e < NE) atomicAdd(&deg[ei[NE + e]], 1);
}

__global__ void k_dinv(const int* __restrict__ deg, float* __restrict__ dinv) {
  int n = blockIdx.x * 256 + threadIdx.x;
  if (n < NN) dinv[n] = __fdiv_rn(1.0f, __fsqrt_rn((float)(deg[n] + 1)));  // +1 self-loop
}

__global__ void k_scan(const int* __restrict__ deg, int* __restrict__ rowp) {
  __shared__ int sdata[1024];
  int tid = threadIdx.x;
  int base = tid * 16;
  int loc[16];
  int sum = 0;
  #pragma unroll
  for (int i = 0; i < 16; ++i) { loc[i] = sum; sum += deg[base + i]; }
  sdata[tid] = sum;
  __syncthreads();
  for (int off = 1; off < 1024; off <<= 1) {
    int v = 0;
    if (tid >= off) v = sdata[tid - off];
    __syncthreads();
    sdata[tid] += v;
    __syncthreads();
  }
  int excl = (tid == 0) ? 0 : sdata[tid - 1];
  #pragma unroll
  for (int i = 0; i < 16; ++i) rowp[base + i] = excl + loc[i];
  if (tid == 1023) rowp[NN] = sdata[1023];
}

__global__ void k_scatter(const int* __restrict__ ei, const int* __restrict__ rowp,
                          int* __restrict__ fill, int* __restrict__ eid) {
  int e = blockIdx.x * 256 + threadIdx.x;
  if (e >= NE) return;
  int d = ei[NE + e];
  int pos = rowp[d] + atomicAdd(&fill[d], 1);
  eid[pos] = e;
}

// sort each adjacency list by EDGE ID (unique keys) -> summation order == scatter-add order
__global__ void k_sortadj(const int* __restrict__ rowp, int* __restrict__ eid,
                          const int* __restrict__ ei, const float* __restrict__ dinv,
                          int* __restrict__ col, float* __restrict__ colw) {
  int d = blockIdx.x * 256 + threadIdx.x;
  if (d >= NN) return;
  int r0 = rowp[d], r1 = rowp[d + 1];
  for (int i = r0 + 1; i < r1; ++i) {
    int key = eid[i];
    int j = i - 1;
    while (j >= r0 && eid[j] > key) { eid[j + 1] = eid[j]; --j; }
    eid[j + 1] = key;
  }
  for (int i = r0; i < r1; ++i) {
    int s = ei[eid[i]];
    col[i] = s;
    colw[i] = dinv[s];
  }
}

// ---------------- per-timestep kernels ----------------
// enc LIF (2 nodes/block; x staged through LDS to kill strided scalar loads)
__global__ __launch_bounds__(256) void k_enc(
    const float* __restrict__ x, const float* __restrict__ encW, const float* __restrict__ encB,
    float* __restrict__ enc_mem, float* __restrict__ enc_spk, int t) {
  __shared__ float xs[2][8];
  int tid = threadIdx.x;
  int nb = blockIdx.x * 2;
  if (tid < 16)
    xs[tid >> 3][tid & 7] = x[(size_t)(nb + (tid >> 3)) * 256 + (size_t)(tid & 7) * 32 + t];
  __syncthreads();
  int nl = tid >> 7, j = tid & 127;
  int idx = (nb + nl) * 128 + j;
  float dot = 0.f;
  #pragma unroll
  for (int c = 0; c < 8; ++c) dot = __fmaf_rn(xs[nl][c], encW[c * 128 + j], dot);
  float m = enc_mem[idx], s = enc_spk[idx];
  float nm = __fadd_rn(__fadd_rn(__fmul_rn(__fmul_rn(m, 0.2f), __fsub_rn(1.f, s)), dot), encB[j]);
  enc_mem[idx] = nm;
  enc_spk[idx] = nm > 0.5f ? 1.f : 0.f;
}

// bases = spk @ bases_W + b ; comb = spk @ comb_W + b
// lane = node (64/block), 32 independent channel chains per lane.
// Wave roles: w0 bases ch0-31, w1 bases ch32-63, w2 comb ch0-15, w3 comb ch16-31.
// Spike: 1 ds_read_b32/j (2-way wrap, free). Weights: lane-invariant addr -> s_load.
// Per-output chain: fma ascending j from 0, then +bias == round-3 chain (bit-exact).
__global__ __launch_bounds__(256) void k_bases_comb(
    const float* __restrict__ enc_spk,
    const float* __restrict__ basesW, const float* __restrict__ basesB,
    const float* __restrict__ combW, const float* __restrict__ combB,
    float* __restrict__ bases, float* __restrict__ comb) {
  __shared__ float sp[64 * 129];   // [node][j], pad 129 -> (n+j)%32 banks
  __shared__ float ob[64 * 65];    // bases out [node][ch], pad 65
  __shared__ float oc[64 * 33];    // comb out [node][ch], pad 33
  const int tid = threadIdx.x;
  const int nb = blockIdx.x * 64;
  // stage spikes: idx = k*256+tid -> per-wave node is constant -> conflict-free writes
  #pragma unroll 4
  for (int k = 0; k < 32; ++k) {
    int idx = k * 256 + tid;
    int n = idx >> 7, j = idx & 127;
    sp[n * 129 + j] = enc_spk[(size_t)nb * 128 + idx];
  }
  __syncthreads();
  const int lane = tid & 63;
  const int w = tid >> 6;
  const float* spn = sp + lane * 129;
  if (w < 2) {
    const int ch0 = w * 32;
    const float* Wp = basesW + ch0;
    float acc[32];
    #pragma unroll
    for (int c = 0; c < 32; ++c) acc[c] = 0.f;
    for (int j = 0; j < 128; ++j) {
      const float s = spn[j];
      const float* wr = Wp + j * 64;     // lane-invariant -> scalar loads
      #pragma unroll
      for (int c = 0; c < 32; ++c) acc[c] = __fmaf_rn(s, wr[c], acc[c]);
    }
    #pragma unroll
    for (int c = 0; c < 32; ++c) ob[lane * 65 + ch0 + c] = acc[c];
  } else {
    const int ch0 = (w - 2) * 16;
    const float* Wp = combW + ch0;
    float acc[16];
    #pragma unroll
    for (int c = 0; c < 16; ++c) acc[c] = 0.f;
    for (int j = 0; j < 128; ++j) {
      const float s = spn[j];
      const float* wr = Wp + j * 32;
      #pragma unroll
      for (int c = 0; c < 16; ++c) acc[c] = __fmaf_rn(s, wr[c], acc[c]);
    }
    #pragma unroll
    for (int c = 0; c < 16; ++c) oc[lane * 33 + ch0 + c] = acc[c];
  }
  __syncthreads();
  // coalesced stores with bias
  #pragma unroll
  for (int r = 0; r < 16; ++r) {
    int idx = r * 256 + tid;
    int n = idx >> 6, ch = idx & 63;
    bases[(size_t)(nb + n) * 64 + ch] = __fadd_rn(ob[n * 65 + ch], basesB[ch]);
  }
  #pragma unroll
  for (int r = 0; r < 8; ++r) {
    int idx = r * 256 + tid;
    int n = idx >> 5, ch = idx & 31;
    comb[(size_t)(nb + n) * 32 + ch] = __fadd_rn(oc[n * 33 + ch], combB[ch]);
  }
}

// fused: symnorm aggregation (edge-order scatter-add) -> einsum -> conv LIF -> c1 spike
__global__ __launch_bounds__(256) void k_aggconv(
    const float* __restrict__ bases, const float* __restrict__ comb,
    const float* __restrict__ dinv, const int* __restrict__ rowp,
    const int* __restrict__ col, const float* __restrict__ colw,
    const float* __restrict__ convB,
    float* __restrict__ c1_mem, float* __restrict__ c1_spk) {
  __shared__ float aggl[4][64];
  __shared__ float combl[4][32];
  int w = threadIdx.x >> 6;
  int m = threadIdx.x & 63;
  int d = blockIdx.x * 4 + w;
  float dd = dinv[d];
  int r0 = rowp[d], r1 = rowp[d + 1];
  float acc = 0.f;
  for (int r = r0; r < r1; ++r) {
    int s = col[r];
    float ew  = __fmul_rn(colw[r], dd);
    float upd = __fmul_rn(ew, bases[(size_t)s * 64 + m]);
    acc = __fadd_rn(acc, upd);
  }
  {
    float ew  = __fmul_rn(dd, dd);
    float upd = __fmul_rn(ew, bases[(size_t)d * 64 + m]);
    acc = __fadd_rn(acc, upd);
  }
  aggl[w][m] = acc;
  if (m < 32) combl[w][m] = comb[(size_t)d * 32 + m];
  __syncthreads();
  #pragma unroll
  for (int half = 0; half < 2; ++half) {
    int j = m + half * 64;
    int h = j >> 4, f = j & 15;
    float cv = 0.f;
    #pragma unroll
    for (int b = 0; b < 4; ++b)
      cv = __fadd_rn(cv, __fmul_rn(combl[w][h * 4 + b], aggl[w][b * 16 + f]));
    cv = __fadd_rn(cv, convB[j]);
    int idx = d * 128 + j;
    float cm = c1_mem[idx], cs = c1_spk[idx];
    float nm = __fadd_rn(__fmul_rn(__fmul_rn(cm, 0.2f), __fsub_rn(1.f, cs)), cv);
    c1_mem[idx] = nm;
    c1_spk[idx] = nm > 0.5f ? 1.f : 0.f;
  }
}

// one BLAS panel of the gates GEMM: part[z] = A[:, panel_z] @ B[panel_z, :]
__global__ __launch_bounds__(256) void k_gpanel(
    const float* __restrict__ xl, const float* __restrict__ lh,
    const float* __restrict__ Wih, const float* __restrict__ Whh,
    float* __restrict__ part) {
  __shared__ __align__(16) float Ast[16][132];   // [k][m] transposed
  __shared__ __align__(16) float Bs[16][132];    // [k][n]
  const int tid = threadIdx.x;
  const int tx = tid & 15, ty = tid >> 4;
  const int n0 = blockIdx.x * 128;
  const int m0 = blockIdx.y * 128;
  const int z  = blockIdx.z;

  const float* Asrc; const float* Bsrc; int lda, k0, klen;
  if (z < 22) { Asrc = xl; Bsrc = Wih; lda = 8192; k0 = z * 384; klen = (z == 21) ? 128 : 384; }
  else        { Asrc = lh; Bsrc = Whh; lda = 512;  k0 = (z == 22) ? 0 : 384; klen = (z == 22) ? 384 : 128; }

  float acc[8][8];
  #pragma unroll
  for (int i = 0; i < 8; ++i)
    #pragma unroll
    for (int j = 0; j < 8; ++j) acc[i][j] = 0.f;

  const int arow = tid >> 1;            // 0..127
  const int acol = (tid & 1) * 8;       // 0 or 8
  const int brow = tid >> 5;            // 0..7 (and +8)
  const int bcol = (tid & 31) * 4;      // 0..124

  const int nkt = klen >> 4;
  for (int kt = 0; kt < nkt; ++kt) {
    const int kb = k0 + (kt << 4);
    __syncthreads();
    {   // A tile -> transposed LDS
      const float* src = Asrc + (size_t)(m0 + arow) * lda + kb + acol;
      const float4 v0 = ((const float4*)src)[0];
      const float4 v1 = ((const float4*)src)[1];
      Ast[acol + 0][arow] = v0.x; Ast[acol + 1][arow] = v0.y;
      Ast[acol + 2][arow] = v0.z; Ast[acol + 3][arow] = v0.w;
      Ast[acol + 4][arow] = v1.x; Ast[acol + 5][arow] = v1.y;
      Ast[acol + 6][arow] = v1.z; Ast[acol + 7][arow] = v1.w;
    }
    {   // B tile (2 rows per thread, fully coalesced 16B chunks)
      *(float4*)&Bs[brow][bcol] =
          *(const float4*)(Bsrc + (size_t)(kb + brow) * 2048 + n0 + bcol);
      *(float4*)&Bs[brow + 8][bcol] =
          *(const float4*)(Bsrc + (size_t)(kb + brow + 8) * 2048 + n0 + bcol);
    }
    __syncthreads();
    #pragma unroll
    for (int kk = 0; kk < 16; ++kk) {
      const float4 a0 = *(const float4*)&Ast[kk][ty * 4];
      const float4 a1 = *(const float4*)&Ast[kk][64 + ty * 4];
      const float4 b0 = *(const float4*)&Bs[kk][tx * 4];
      const float4 b1 = *(const float4*)&Bs[kk][64 + tx * 4];
      const float av[8] = {a0.x, a0.y, a0.z, a0.w, a1.x, a1.y, a1.z, a1.w};
      const float bv[8] = {b0.x, b0.y, b0.z, b0.w, b1.x, b1.y, b1.z, b1.w};
      #pragma unroll
      for (int i = 0; i < 8; ++i)
        #pragma unroll
        for (int j = 0; j < 8; ++j)
          acc[i][j] = __fmaf_rn(av[i], bv[j], acc[i][j]);
    }
  }
  float* dstz = part + (size_t)z * GSTRIDE + (size_t)m0 * 2048 + n0;
  #pragma unroll
  for (int i = 0; i < 8; ++i) {
    const int mr = ((i >> 2) << 6) + ty * 4 + (i & 3);
    float* row = dstz + (size_t)mr * 2048;
    *(float4*)(row + tx * 4)      = make_float4(acc[i][0], acc[i][1], acc[i][2], acc[i][3]);
    *(float4*)(row + 64 + tx * 4) = make_float4(acc[i][4], acc[i][5], acc[i][6], acc[i][7]);
  }
}

// combine panel partials strictly left-to-right (matches round-2 "tih += accP" chain)
__global__ __launch_bounds__(256) void k_combine(
    const float* __restrict__ part, const float* __restrict__ bih,
    const float* __restrict__ bhh, float* __restrict__ gates) {
  const int idx = blockIdx.x * 256 + threadIdx.x;    // m*2048 + u
  const float* p = part + idx;
  float tih = p[0];
  #pragma unroll
  for (int zz = 1; zz < 22; ++zz) tih = __fadd_rn(tih, p[(size_t)zz * GSTRIDE]);
  const float thh = __fadd_rn(p[22u * GSTRIDE], p[23u * GSTRIDE]);
  const int u = idx & 2047;
  gates[idx] = __fadd_rn(__fadd_rn(__fadd_rn(tih, bih[u]), thh), bhh[u]);
}

// fused: gate spikes -> LSTM cell -> fc1 LIF (384+128 panels) -> fc2 LIF -> h2 accum
__global__ __launch_bounds__(256) void k_cell(
    const float* __restrict__ gates,
    float* __restrict__ lc, float* __restrict__ lh,
    const float* __restrict__ fc1W, const float* __restrict__ fc1b,
    const float* __restrict__ fc2W, const float* __restrict__ fc2b,
    float* __restrict__ h1_mem, float* __restrict__ h1_spk,
    float* __restrict__ h2_mem, float* __restrict__ h2_spk, float* __restrict__ h2_sum) {
  __shared__ float lhl[512];
  __shared__ float sp1l[256];
  const int s = blockIdx.x;
  const int p = threadIdx.x;
  #pragma unroll
  for (int half = 0; half < 2; ++half) {
    const int h = p + half * 256;
    const float giv = gates[(size_t)s * 2048 + h];
    const float gfv = gates[(size_t)s * 2048 + 512 + h];
    const float ggv = gates[(size_t)s * 2048 + 1024 + h];
    const float gov = gates[(size_t)s * 2048 + 1536 + h];
    const float iv = giv > 0.f ? 1.f : 0.f;
    const float fv = gfv > 0.f ? 1.f : 0.f;
    const float gv = ggv > 0.f ? 1.f : 0.f;
    const float ov = gov > 0.f ? 1.f : 0.f;
    const int li = s * 512 + h;
    const float lcv = __fadd_rn(__fmul_rn(fv, lc[li]), __fmul_rn(iv, gv));
    lc[li] = lcv;
    const float lhv = __fmul_rn(lcv, ov);
    lh[li] = lhv;
    lhl[h] = lhv;
  }
  __syncthreads();
  float a0 = 0.f, a1 = 0.f;
  #pragma unroll 8
  for (int q = 0; q < 384; ++q) a0 = __fmaf_rn(lhl[q], fc1W[q * 256 + p], a0);
  #pragma unroll 8
  for (int q = 384; q < 512; ++q) a1 = __fmaf_rn(lhl[q], fc1W[q * 256 + p], a1);
  const float dot1 = __fadd_rn(a0, a1);
  const int i1 = s * 256 + p;
  const float m1 = h1_mem[i1], s1o = h1_spk[i1];
  const float nm1 = __fadd_rn(__fadd_rn(__fmul_rn(__fmul_rn(m1, 0.2f), __fsub_rn(1.f, s1o)), dot1), fc1b[p]);
  h1_mem[i1] = nm1;
  const float sp1 = nm1 > 0.5f ? 1.f : 0.f;
  h1_spk[i1] = sp1;
  sp1l[p] = sp1;
  __syncthreads();
  if (p < 4) {
    float acc = 0.f;
    for (int q = 0; q < 256; ++q) acc = __fmaf_rn(sp1l[q], fc2W[q * 4 + p], acc);
    const int i2 = s * 4 + p;
    const float m2 = h2_mem[i2], s2o = h2_spk[i2];
    const float nm2 = __fadd_rn(__fadd_rn(__fmul_rn(__fmul_rn(m2, 0.2f), __fsub_rn(1.f, s2o)), acc), fc2b[p]);
    h2_mem[i2] = nm2;
    const float sp2 = nm2 > 0.5f ? 1.f : 0.f;
    h2_spk[i2] = sp2;
    h2_sum[i2] = __fadd_rn(h2_sum[i2], sp2);
  }
}

__global__ void k_out(const float* __restrict__ h2_sum, float* __restrict__ out) {
  int i = blockIdx.x * 256 + threadIdx.x;
  if (i < SG * 4) out[i] = __fmul_rn(h2_sum[i], 0.03125f);
}

// ---------------- launch ----------------
extern "C" void kernel_launch(void* const* d_in, const int* in_sizes, int n_in,
                              void* d_out, int out_size, void* d_ws, size_t ws_size,
                              hipStream_t stream) {
  const float* x      = (const float*)d_in[0];
  const int*   ei     = (const int*)  d_in[1];
  const float* encW   = (const float*)d_in[2];
  const float* encB   = (const float*)d_in[3];
  const float* basesW = (const float*)d_in[4];
  const float* basesB = (const float*)d_in[5];
  const float* combW  = (const float*)d_in[6];
  const float* combB  = (const float*)d_in[7];
  const float* convB  = (const float*)d_in[8];
  const float* Wih    = (const float*)d_in[9];
  const float* Whh    = (const float*)d_in[10];
  const float* bih    = (const float*)d_in[11];
  const float* bhh    = (const float*)d_in[12];
  const float* fc1W   = (const float*)d_in[13];
  const float* fc1b   = (const float*)d_in[14];
  const float* fc2W   = (const float*)d_in[15];
  const float* fc2b   = (const float*)d_in[16];

  float* ws = (float*)d_ws;
  float* enc_mem = ws + OFF_ENC_MEM;
  float* enc_spk = ws + OFF_ENC_SPK;
  float* c1_mem  = ws + OFF_C1_MEM;
  float* c1_spk  = ws + OFF_C1_SPK;   // xl
  float* lhp     = ws + OFF_LH;
  float* lcp     = ws + OFF_LC;
  float* h1_mem  = ws + OFF_H1_MEM;
  float* h1_spk  = ws + OFF_H1_SPK;
  float* h2_mem  = ws + OFF_H2_MEM;
  float* h2_spk  = ws + OFF_H2_SPK;
  float* h2_sum  = ws + OFF_H2_SUM;
  float* bases   = ws + OFF_BASES;
  float* comb    = ws + OFF_COMB;
  float* gates   = ws + OFF_GATES;
  float* partp   = ws + OFF_PART;
  float* dinv    = ws + OFF_DINV;
  float* colw    = ws + OFF_COLW;
  int* ibase = (int*)((char*)d_ws + (size_t)FLOAT_END * 4);
  int* deg  = ibase + IOFF_DEG;
  int* fill = ibase + IOFF_FILL;
  int* rowp = ibase + IOFF_ROWPTR;
  int* eid  = ibase + IOFF_EID;
  int* col  = ibase + IOFF_COL;

  hipMemsetAsync(ws, 0, (size_t)ZERO_FLOATS * 4, stream);
  hipMemsetAsync(ibase, 0, 32768 * 4, stream);

  k_deg    <<<NE / 256, 256, 0, stream>>>(ei, deg);
  k_dinv   <<<NN / 256, 256, 0, stream>>>(deg, dinv);
  k_scan   <<<1, 1024, 0, stream>>>(deg, rowp);
  k_scatter<<<NE / 256, 256, 0, stream>>>(ei, rowp, fill, eid);
  k_sortadj<<<NN / 256, 256, 0, stream>>>(rowp, eid, ei, dinv, col, colw);

  for (int t = 0; t < TSTEPS; ++t) {
    k_enc       <<<NN / 2, 256, 0, stream>>>(x, encW, encB, enc_mem, enc_spk, t);
    k_bases_comb<<<NN / 64, 256, 0, stream>>>(enc_spk, basesW, basesB, combW, combB, bases, comb);
    k_aggconv   <<<NN / 4, 256, 0, stream>>>(bases, comb, dinv, rowp, col, colw, convB, c1_mem, c1_spk);
    k_gpanel    <<<dim3(16, 2, NPANEL), 256, 0, stream>>>(c1_spk, lhp, Wih, Whh, partp);
    k_combine   <<<2048, 256, 0, stream>>>(partp, bih, bhh, gates);
    k_cell      <<<SG, 256, 0, stream>>>(gates, lcp, lhp, fc1W, fc1b, fc2W, fc2b,
                                         h1_mem, h1_spk, h2_mem, h2_spk, h2_sum);
  }
  k_out<<<4, 256, 0, stream>>>(h2_sum, (float*)d_out);
}